// Round 4
// baseline (5024.727 us; speedup 1.0000x reference)
//
#include <hip/hip_runtime.h>
#include <hip/hip_bf16.h>
#include <math.h>

// ---------------------------------------------------------------------------
// VQGAN forward, fp32, round 4.
//  - Convs: weights staged in LDS (32KB ci-chunks) -> no SGPR-starved s_load
//    stalls; inner loop reads weights via broadcast ds_read_b128.
//  - ConvT: 2-wide j tile, float2 loads / float4 stores, LDS weights.
//  - GroupNorm: 2-kernel deterministic (partial stats -> combine+apply).
//  - FMA order per output unchanged (ci -> taps) => conv numerics identical.
// d_out = [recon 16*3*256*256 | q 16*32*32*32 | idx-as-float 16384]
// ---------------------------------------------------------------------------

#define EPS 1e-5f

// ---------------- LDS weight staging (coalesced, float4) -------------------
template <int Cin, int CO_T, int CICHUNK>
__device__ __forceinline__ void stage_weights(
    const float* __restrict__ wb, int ci0, float4* __restrict__ lds4)
{
    constexpr int W4 = CICHUNK * CO_T * 4;     // float4s per chunk
    for (int g4 = threadIdx.x; g4 < W4; g4 += 256) {
        int u  = g4 / (CICHUNK * 4);
        int r4 = g4 - u * (CICHUNK * 4);
        float4 v = ((const float4*)(wb + (size_t)u * Cin * 16 + (size_t)ci0 * 16))[r4];
        int cic = r4 >> 2, qq = r4 & 3;
        lds4[(cic * CO_T + u) * 4 + qq] = v;
    }
}

// ===================== conv k4 s2 p1, CO_T channels/thread =================
template <int Cin, int Cout, int Hin, int Win, int CO_T, int CICHUNK>
__global__ __launch_bounds__(256) void conv4s2_lds(
    const float* __restrict__ x, const float* __restrict__ w,
    const float* __restrict__ bias, float* __restrict__ y)
{
    constexpr int Hout = Hin / 2, Wout = Win / 2, Wt = Wout / 4;
    __shared__ float4 wlds[CICHUNK * CO_T * 4];

    const int n   = blockIdx.z;              // SGPR
    const int co0 = blockIdx.y * CO_T;       // SGPR
    const int local = blockIdx.x * 256 + threadIdx.x;
    const int wt = local & (Wt - 1);
    const int oh = local / Wt;
    const int iw0 = (wt << 3) - 1;
    const int ih0 = (oh << 1) - 1;

    const float* __restrict__ xn = x + (size_t)n * Cin * Hin * Win;
    const float* __restrict__ wb = w + (size_t)co0 * Cin * 16;

    const bool cL = (wt > 0);
    const bool cR = (wt < Wt - 1);

    float acc[CO_T][4];
    #pragma unroll
    for (int u = 0; u < CO_T; ++u)
        acc[u][0] = acc[u][1] = acc[u][2] = acc[u][3] = 0.f;

    bool rv[4]; int ro[4];
    #pragma unroll
    for (int k = 0; k < 4; ++k) {
        int r = ih0 + k;
        rv[k] = (r >= 0) && (r < Hin);
        ro[k] = rv[k] ? r : 0;
    }

    for (int ci0 = 0; ci0 < Cin; ci0 += CICHUNK) {
        if (ci0) __syncthreads();
        stage_weights<Cin, CO_T, CICHUNK>(wb, ci0, wlds);
        __syncthreads();

        for (int cic = 0; cic < CICHUNK; ++cic) {
            const int ci = ci0 + cic;
            const float* xp = xn + (size_t)ci * Hin * Win;
            float xv[4][10];
            #pragma unroll
            for (int k = 0; k < 4; ++k) {
                const float* rp = xp + (size_t)ro[k] * Win;
                float4 m0 = *(const float4*)(rp + (wt << 3));
                float4 m1 = *(const float4*)(rp + (wt << 3) + 4);
                float e0 = cL ? rp[iw0] : 0.f;
                float e9 = cR ? rp[iw0 + 9] : 0.f;
                bool rk = rv[k];
                xv[k][0] = rk ? e0   : 0.f;
                xv[k][1] = rk ? m0.x : 0.f;
                xv[k][2] = rk ? m0.y : 0.f;
                xv[k][3] = rk ? m0.z : 0.f;
                xv[k][4] = rk ? m0.w : 0.f;
                xv[k][5] = rk ? m1.x : 0.f;
                xv[k][6] = rk ? m1.y : 0.f;
                xv[k][7] = rk ? m1.z : 0.f;
                xv[k][8] = rk ? m1.w : 0.f;
                xv[k][9] = rk ? e9   : 0.f;
            }
            #pragma unroll
            for (int u = 0; u < CO_T; ++u) {
                const int wbase = (cic * CO_T + u) * 4;
                float4 wq[4];
                wq[0] = wlds[wbase + 0];
                wq[1] = wlds[wbase + 1];
                wq[2] = wlds[wbase + 2];
                wq[3] = wlds[wbase + 3];
                #pragma unroll
                for (int kh = 0; kh < 4; ++kh) {
                    float wv0 = wq[kh].x, wv1 = wq[kh].y, wv2 = wq[kh].z, wv3 = wq[kh].w;
                    acc[u][0] = fmaf(xv[kh][0], wv0, acc[u][0]);
                    acc[u][1] = fmaf(xv[kh][2], wv0, acc[u][1]);
                    acc[u][2] = fmaf(xv[kh][4], wv0, acc[u][2]);
                    acc[u][3] = fmaf(xv[kh][6], wv0, acc[u][3]);
                    acc[u][0] = fmaf(xv[kh][1], wv1, acc[u][0]);
                    acc[u][1] = fmaf(xv[kh][3], wv1, acc[u][1]);
                    acc[u][2] = fmaf(xv[kh][5], wv1, acc[u][2]);
                    acc[u][3] = fmaf(xv[kh][7], wv1, acc[u][3]);
                    acc[u][0] = fmaf(xv[kh][2], wv2, acc[u][0]);
                    acc[u][1] = fmaf(xv[kh][4], wv2, acc[u][1]);
                    acc[u][2] = fmaf(xv[kh][6], wv2, acc[u][2]);
                    acc[u][3] = fmaf(xv[kh][8], wv2, acc[u][3]);
                    acc[u][0] = fmaf(xv[kh][3], wv3, acc[u][0]);
                    acc[u][1] = fmaf(xv[kh][5], wv3, acc[u][1]);
                    acc[u][2] = fmaf(xv[kh][7], wv3, acc[u][2]);
                    acc[u][3] = fmaf(xv[kh][9], wv3, acc[u][3]);
                }
            }
        }
    }

    #pragma unroll
    for (int u = 0; u < CO_T; ++u) {
        float b = bias[co0 + u];
        float4 o;
        o.x = acc[u][0] + b; o.y = acc[u][1] + b;
        o.z = acc[u][2] + b; o.w = acc[u][3] + b;
        float* yp = y + (((size_t)(n * Cout + co0 + u)) * Hout + oh) * Wout + (wt << 2);
        *(float4*)yp = o;
    }
}

// ==================== GroupNorm stats (partial, 2-stage) ===================
// grid: (K, 512). Each block: partial sum/sumsq of chunk k of group bg.
__global__ __launch_bounds__(256) void gn_stats(
    const float* __restrict__ y, float2* __restrict__ part,
    int HWshift, int grpC, int K)
{
    const int kblk = blockIdx.x;
    const int bg = blockIdx.y;
    const int b = bg >> 5, g = bg & 31;
    const int C = grpC << 5;
    const size_t base = ((size_t)b * C + (size_t)g * grpC) << HWshift;
    const int count4 = (grpC << HWshift) >> 2;
    const int chunk4 = count4 / K;
    const int ofs4 = kblk * chunk4;
    const float4* y4 = (const float4*)(y + base);

    float s = 0.f, ss = 0.f;
    for (int i = ofs4 + threadIdx.x; i < ofs4 + chunk4; i += 256) {
        float4 v = y4[i];
        s += v.x + v.y + v.z + v.w;
        ss = fmaf(v.x, v.x, ss); ss = fmaf(v.y, v.y, ss);
        ss = fmaf(v.z, v.z, ss); ss = fmaf(v.w, v.w, ss);
    }
    __shared__ float sh0[256];
    __shared__ float sh1[256];
    sh0[threadIdx.x] = s; sh1[threadIdx.x] = ss;
    __syncthreads();
    for (int off = 128; off > 0; off >>= 1) {
        if (threadIdx.x < off) {
            sh0[threadIdx.x] += sh0[threadIdx.x + off];
            sh1[threadIdx.x] += sh1[threadIdx.x + off];
        }
        __syncthreads();
    }
    if (threadIdx.x == 0) {
        float2 p; p.x = sh0[0]; p.y = sh1[0];
        part[bg * K + kblk] = p;
    }
}

// ============== GroupNorm combine + normalize + SiLU (in place) ============
__global__ __launch_bounds__(256) void gn_apply(
    float* __restrict__ y, const float* __restrict__ gamma,
    const float* __restrict__ beta, const float2* __restrict__ part,
    int HWshift, int grpC, int K)
{
    const int kblk = blockIdx.x;
    const int bg = blockIdx.y;
    const int b = bg >> 5, g = bg & 31;
    const int C = grpC << 5;
    const size_t base = ((size_t)b * C + (size_t)g * grpC) << HWshift;
    const int count4 = (grpC << HWshift) >> 2;
    const int chunk4 = count4 / K;
    const int ofs4 = kblk * chunk4;
    float4* y4 = (float4*)(y + base);

    // fixed ascending order => deterministic, identical in every block
    float s = 0.f, ss = 0.f;
    for (int k = 0; k < K; ++k) {
        float2 p = part[bg * K + k];
        s += p.x; ss += p.y;
    }
    const float inv = 1.f / (float)(count4 * 4);
    const float mean = s * inv;
    const float var  = ss * inv - mean * mean;
    const float rstd = rsqrtf(var + EPS);

    const int HW4shift = HWshift - 2;
    for (int i = ofs4 + threadIdx.x; i < ofs4 + chunk4; i += 256) {
        int c = g * grpC + (i >> HW4shift);
        float ga = gamma[c], be = beta[c];
        float4 v = y4[i];
        float t0 = (v.x - mean) * rstd * ga + be;
        float t1 = (v.y - mean) * rstd * ga + be;
        float t2 = (v.z - mean) * rstd * ga + be;
        float t3 = (v.w - mean) * rstd * ga + be;
        v.x = t0 / (1.f + __expf(-t0));
        v.y = t1 / (1.f + __expf(-t1));
        v.z = t2 / (1.f + __expf(-t2));
        v.w = t3 / (1.f + __expf(-t3));
        y4[i] = v;
    }
}

// ====================== 1x1 conv, CO_T channels/thread =====================
template <int Cin, int Cout, int HW, int CO_T>
__global__ __launch_bounds__(256) void conv1x1_k(
    const float* __restrict__ x, const float* __restrict__ w,
    const float* __restrict__ bias, float* __restrict__ y)
{
    const int n   = blockIdx.z;
    const int co0 = blockIdx.y * CO_T;
    const int s = blockIdx.x * 256 + threadIdx.x;
    const float* xp = x + (size_t)n * Cin * HW + s;

    float acc[CO_T];
    #pragma unroll
    for (int u = 0; u < CO_T; ++u) acc[u] = bias[co0 + u];

    for (int ci = 0; ci < Cin; ++ci) {
        float v = xp[(size_t)ci * HW];
        #pragma unroll
        for (int u = 0; u < CO_T; ++u)
            acc[u] = fmaf(v, w[(size_t)(co0 + u) * Cin + ci], acc[u]);
    }
    #pragma unroll
    for (int u = 0; u < CO_T; ++u)
        y[(size_t)(n * Cout + co0 + u) * HW + s] = acc[u];
}

// ============================== VQ lookup ==================================
__global__ __launch_bounds__(256) void cb_norm(
    const float* __restrict__ cb, float* __restrict__ cn)
{
    int j = blockIdx.x * 256 + threadIdx.x;   // 1024 total
    const float* c = cb + (size_t)j * 32;
    float s = 0.f;
    #pragma unroll
    for (int k = 0; k < 32; ++k) s = fmaf(c[k], c[k], s);
    cn[j] = s;
}

__global__ __launch_bounds__(256) void vq_kernel(
    const float* __restrict__ z, const float* __restrict__ cb,
    const float* __restrict__ cn, float* __restrict__ q,
    float* __restrict__ idxf)
{
    const int row = blockIdx.x * 4 + (threadIdx.x >> 6);
    const int lane = threadIdx.x & 63;
    const float* zr = z + (size_t)row * 32;
    float zreg[32];
    #pragma unroll
    for (int k = 0; k < 32; ++k) zreg[k] = zr[k];
    float zn = 0.f;
    #pragma unroll
    for (int k = 0; k < 32; ++k) zn = fmaf(zreg[k], zreg[k], zn);

    float best = 3.4e38f;
    int bj = 0;
    for (int ii = 0; ii < 16; ++ii) {
        int j = lane * 16 + ii;               // lane-ascending code order
        const float* c = cb + (size_t)j * 32;
        float dot = 0.f;
        #pragma unroll
        for (int k = 0; k < 32; ++k) dot = fmaf(zreg[k], c[k], dot);
        float d = zn + cn[j] - 2.f * dot;
        if (d < best) { best = d; bj = j; }
    }
    #pragma unroll
    for (int off = 1; off < 64; off <<= 1) {
        float ob = __shfl_xor(best, off);
        int   oj = __shfl_xor(bj, off);
        if (ob < best || (ob == best && oj < bj)) { best = ob; bj = oj; }
    }
    if (lane < 32) q[(size_t)row * 32 + lane] = cb[(size_t)bj * 32 + lane];
    if (lane == 0) idxf[row] = (float)bj;
}

// ====== conv transpose k4 s2 p1, 2-wide j tile, CO_T channels/thread ======
template <int Cin, int Cout, int Hin, int Win, int CO_T, int CICHUNK, bool TANH>
__global__ __launch_bounds__(256) void convt2_lds(
    const float* __restrict__ x, const float* __restrict__ w,
    const float* __restrict__ bias, float* __restrict__ y)
{
    constexpr int Wt2 = Win / 2;
    __shared__ float4 wlds[CICHUNK * CO_T * 4];

    const int n   = blockIdx.z;              // SGPR
    const int co0 = blockIdx.y * CO_T;       // SGPR
    const int local = blockIdx.x * 256 + threadIdx.x;
    const int jt = local & (Wt2 - 1);
    const int i  = local / Wt2;
    const int j0 = jt << 1;                  // input cols j0, j0+1 (center)

    const float* __restrict__ xn = x + (size_t)n * Cin * Hin * Win;
    const float* __restrict__ wb = w + (size_t)co0 * Cin * 16;

    const bool rm0 = (i > 0), rm2 = (i + 1 < Hin);
    const bool cmL = (jt > 0), cmR = (jt < Wt2 - 1);
    const int ro0 = rm0 ? (i - 1) : 0;
    const int ro2 = rm2 ? (i + 1) : 0;

    float acc[CO_T][2][4];
    #pragma unroll
    for (int u = 0; u < CO_T; ++u)
        #pragma unroll
        for (int p = 0; p < 2; ++p)
            acc[u][p][0] = acc[u][p][1] = acc[u][p][2] = acc[u][p][3] = 0.f;

    for (int ci0 = 0; ci0 < Cin; ci0 += CICHUNK) {
        if (ci0) __syncthreads();
        stage_weights<Cin, CO_T, CICHUNK>(wb, ci0, wlds);
        __syncthreads();

        for (int cic = 0; cic < CICHUNK; ++cic) {
            const int ci = ci0 + cic;
            const float* xp = xn + (size_t)ci * Hin * Win;
            // patch rows i-1,i,i+1  cols j0-1..j0+2
            float xr[3][4];
            {
                const int rows[3] = {ro0, i, ro2};
                const bool rvn[3] = {rm0, true, rm2};
                #pragma unroll
                for (int r = 0; r < 3; ++r) {
                    const float* rp = xp + (size_t)rows[r] * Win;
                    float2 m = *(const float2*)(rp + j0);
                    float eL = cmL ? rp[j0 - 1] : 0.f;
                    float eR = cmR ? rp[j0 + 2] : 0.f;
                    bool rk = rvn[r];
                    xr[r][0] = rk ? eL  : 0.f;
                    xr[r][1] = rk ? m.x : 0.f;
                    xr[r][2] = rk ? m.y : 0.f;
                    xr[r][3] = rk ? eR  : 0.f;
                }
            }
            #pragma unroll
            for (int u = 0; u < CO_T; ++u) {
                const int wbase = (cic * CO_T + u) * 4;
                float4 wq0 = wlds[wbase + 0];
                float4 wq1 = wlds[wbase + 1];
                float4 wq2 = wlds[wbase + 2];
                float4 wq3 = wlds[wbase + 3];
                #pragma unroll
                for (int p = 0; p < 2; ++p) {
                    float x00 = xr[0][p],     x01 = xr[0][p + 1], x02 = xr[0][p + 2];
                    float x10 = xr[1][p],     x11 = xr[1][p + 1], x12 = xr[1][p + 2];
                    float x20 = xr[2][p],     x21 = xr[2][p + 1], x22 = xr[2][p + 2];
                    float* a = acc[u][p];
                    a[0] = fmaf(x00, wq0.x, a[0]); a[0] = fmaf(x01, wq0.z, a[0]);
                    a[0] = fmaf(x10, wq2.x, a[0]); a[0] = fmaf(x11, wq2.z, a[0]);
                    a[1] = fmaf(x01, wq0.y, a[1]); a[1] = fmaf(x02, wq0.w, a[1]);
                    a[1] = fmaf(x11, wq2.y, a[1]); a[1] = fmaf(x12, wq2.w, a[1]);
                    a[2] = fmaf(x10, wq1.x, a[2]); a[2] = fmaf(x11, wq1.z, a[2]);
                    a[2] = fmaf(x20, wq3.x, a[2]); a[2] = fmaf(x21, wq3.z, a[2]);
                    a[3] = fmaf(x11, wq1.y, a[3]); a[3] = fmaf(x12, wq1.w, a[3]);
                    a[3] = fmaf(x21, wq3.y, a[3]); a[3] = fmaf(x22, wq3.w, a[3]);
                }
            }
        }
    }

    constexpr int Hout = Hin * 2, Wout = Win * 2;
    #pragma unroll
    for (int u = 0; u < CO_T; ++u) {
        float b = bias[co0 + u];
        float r00 = acc[u][0][0] + b, r01 = acc[u][0][1] + b;
        float r02 = acc[u][1][0] + b, r03 = acc[u][1][1] + b;
        float r10 = acc[u][0][2] + b, r11 = acc[u][0][3] + b;
        float r12 = acc[u][1][2] + b, r13 = acc[u][1][3] + b;
        if (TANH) {
            r00 = tanhf(r00); r01 = tanhf(r01); r02 = tanhf(r02); r03 = tanhf(r03);
            r10 = tanhf(r10); r11 = tanhf(r11); r12 = tanhf(r12); r13 = tanhf(r13);
        }
        float* yp = y + (((size_t)(n * Cout + co0 + u)) * Hout + (i << 1)) * Wout + (jt << 2);
        float4 o0; o0.x = r00; o0.y = r01; o0.z = r02; o0.w = r03;
        float4 o1; o1.x = r10; o1.y = r11; o1.z = r12; o1.w = r13;
        *(float4*)yp = o0;
        *(float4*)(yp + Wout) = o1;
    }
}

// ================================ launch ===================================
extern "C" void kernel_launch(void* const* d_in, const int* in_sizes, int n_in,
                              void* d_out, int out_size, void* d_ws, size_t ws_size,
                              hipStream_t stream)
{
    const float* x       = (const float*)d_in[0];
    const float* enc0_w  = (const float*)d_in[1];
    const float* enc0_b  = (const float*)d_in[2];
    const float* enc0_g  = (const float*)d_in[3];
    const float* enc0_bt = (const float*)d_in[4];
    const float* enc1_w  = (const float*)d_in[5];
    const float* enc1_b  = (const float*)d_in[6];
    const float* enc1_g  = (const float*)d_in[7];
    const float* enc1_bt = (const float*)d_in[8];
    const float* enc2_w  = (const float*)d_in[9];
    const float* enc2_b  = (const float*)d_in[10];
    const float* enc2_g  = (const float*)d_in[11];
    const float* enc2_bt = (const float*)d_in[12];
    const float* enc3_w  = (const float*)d_in[13];
    const float* enc3_b  = (const float*)d_in[14];
    const float* codebook= (const float*)d_in[15];
    const float* dec0_w  = (const float*)d_in[16];
    const float* dec0_b  = (const float*)d_in[17];
    const float* dec1_w  = (const float*)d_in[18];
    const float* dec1_b  = (const float*)d_in[19];
    const float* dec1_g  = (const float*)d_in[20];
    const float* dec1_bt = (const float*)d_in[21];
    const float* dec2_w  = (const float*)d_in[22];
    const float* dec2_b  = (const float*)d_in[23];
    const float* dec2_g  = (const float*)d_in[24];
    const float* dec2_bt = (const float*)d_in[25];
    const float* dec3_w  = (const float*)d_in[26];
    const float* dec3_b  = (const float*)d_in[27];

    float* ws = (float*)d_ws;
    float*  A  = ws;                       // 33,554,432 floats (134 MB)
    float*  B  = ws + 33554432;            // 16,777,216 floats (67 MB)
    float*  C  = ws + 50331648;            //  8,388,608 floats (33.6 MB)
    float*  Z  = ws + 58720256;            //    524,288 floats (2 MB)
    float*  CN = ws + 59244544;            //      1,024 floats
    float2* GP = (float2*)(ws + 59245568); //      8,192 float2 (gn partials)

    float* out   = (float*)d_out;
    float* recon = out;                    // 3,145,728 floats
    float* qbuf  = out + 3145728;          //   524,288 floats
    float* idxf  = out + 3670016;          //    16,384 floats

    const dim3 blk(256);
    const int K = 16;
    const dim3 gngrid(K, 512);

    // ---------------- encoder ----------------
    // enc0: 16x3x256x256 -> 16x128x128x128
    conv4s2_lds<3, 128, 256, 256, 8, 3><<<dim3(16, 16, 16), blk, 0, stream>>>(
        x, enc0_w, enc0_b, A);
    gn_stats<<<gngrid, blk, 0, stream>>>(A, GP, 14, 4, K);
    gn_apply<<<gngrid, blk, 0, stream>>>(A, enc0_g, enc0_bt, GP, 14, 4, K);

    // enc1: -> 16x256x64x64
    conv4s2_lds<128, 256, 128, 128, 8, 64><<<dim3(4, 32, 16), blk, 0, stream>>>(
        A, enc1_w, enc1_b, B);
    gn_stats<<<gngrid, blk, 0, stream>>>(B, GP, 12, 8, K);
    gn_apply<<<gngrid, blk, 0, stream>>>(B, enc1_g, enc1_bt, GP, 12, 8, K);

    // enc2: -> 16x512x32x32
    conv4s2_lds<256, 512, 64, 64, 8, 64><<<dim3(1, 64, 16), blk, 0, stream>>>(
        B, enc2_w, enc2_b, C);
    gn_stats<<<gngrid, blk, 0, stream>>>(C, GP, 10, 16, K);
    gn_apply<<<gngrid, blk, 0, stream>>>(C, enc2_g, enc2_bt, GP, 10, 16, K);

    // enc3 1x1: -> z 16x32x32x32
    conv1x1_k<512, 32, 1024, 8><<<dim3(4, 4, 16), blk, 0, stream>>>(
        C, enc3_w, enc3_b, Z);

    // ---------------- VQ ----------------
    cb_norm<<<dim3(4), blk, 0, stream>>>(codebook, CN);
    vq_kernel<<<dim3(16384 / 4), blk, 0, stream>>>(Z, codebook, CN, qbuf, idxf);

    // ---------------- decoder ----------------
    // dec0 1x1: q -> 16x512x32x32 (into A)
    conv1x1_k<32, 512, 1024, 8><<<dim3(4, 64, 16), blk, 0, stream>>>(
        qbuf, dec0_w, dec0_b, A);

    // dec1 convT: -> 16x256x64x64 (into B)
    convt2_lds<512, 256, 32, 32, 8, 64, false><<<dim3(2, 32, 16), blk, 0, stream>>>(
        A, dec1_w, dec1_b, B);
    gn_stats<<<gngrid, blk, 0, stream>>>(B, GP, 12, 8, K);
    gn_apply<<<gngrid, blk, 0, stream>>>(B, dec1_g, dec1_bt, GP, 12, 8, K);

    // dec2 convT: -> 16x128x128x128 (into A)
    convt2_lds<256, 128, 64, 64, 8, 64, false><<<dim3(8, 16, 16), blk, 0, stream>>>(
        B, dec2_w, dec2_b, A);
    gn_stats<<<gngrid, blk, 0, stream>>>(A, GP, 14, 4, K);
    gn_apply<<<gngrid, blk, 0, stream>>>(A, dec2_g, dec2_bt, GP, 14, 4, K);

    // dec3 convT + tanh: -> recon 16x3x256x256
    convt2_lds<128, 3, 128, 128, 3, 128, true><<<dim3(32, 1, 16), blk, 0, stream>>>(
        A, dec3_w, dec3_b, recon);
}